// Round 11
// baseline (1933.232 us; speedup 1.0000x reference)
//
#include <hip/hip_runtime.h>
#include <cstdint>
#include <cstddef>

// Problem constants (SparseLinear: B=4096, IN=4096, OUT=4096, NNZ=1677722)
#define IN_F  4096
#define OUT_F 4096
#define BATCH 4096

typedef __bf16 bf16_t;
typedef __bf16 bf16x8 __attribute__((ext_vector_type(8)));
typedef float  f32x4  __attribute__((ext_vector_type(4)));
typedef float  f32x16 __attribute__((ext_vector_type(16)));

// ---------------------------------------------------------------------------
// f32 -> bf16 round-to-nearest-even (bit trick, deterministic)
// ---------------------------------------------------------------------------
__device__ __forceinline__ unsigned short f32_to_bf16_rne(float f) {
  union { float f; unsigned int u; } v;
  v.f = f;
  unsigned int u = v.u;
  return (unsigned short)((u + 0x7FFFu + ((u >> 16) & 1u)) >> 16);
}

__device__ __forceinline__ uint4 cvt8(float4 a, float4 b) {
  uint4 o;
  o.x = (unsigned)f32_to_bf16_rne(a.x) | ((unsigned)f32_to_bf16_rne(a.y) << 16);
  o.y = (unsigned)f32_to_bf16_rne(a.z) | ((unsigned)f32_to_bf16_rne(a.w) << 16);
  o.z = (unsigned)f32_to_bf16_rne(b.x) | ((unsigned)f32_to_bf16_rne(b.y) << 16);
  o.w = (unsigned)f32_to_bf16_rne(b.z) | ((unsigned)f32_to_bf16_rne(b.w) << 16);
  return o;
}

// ---------------------------------------------------------------------------
// Fused: zero the bf16 W buffer AND convert x -> bf16. Grid-stride, high
// occupancy (R9 lesson: do NOT run these phases at GEMM occupancy).
// ---------------------------------------------------------------------------
#define WU16   ((OUT_F * IN_F) / 8)   // 16B units of Wbf (2097152)
#define XUNITS ((BATCH * IN_F) / 8)   // 8-elem units of x (2097152)

__global__ __launch_bounds__(256) void init_zero_cvtx(
    uint4* __restrict__ Wbfv, const float4* __restrict__ xin,
    uint4* __restrict__ xbf) {
  const uint4 z = {0u, 0u, 0u, 0u};
  for (int u = blockIdx.x * 256 + threadIdx.x; u < WU16 + XUNITS;
       u += gridDim.x * 256) {
    if (u < WU16) {
      Wbfv[u] = z;
    } else {
      const int i = u - WU16;
      xbf[i] = cvt8(xin[2 * i], xin[2 * i + 1]);
    }
  }
}

// ---------------------------------------------------------------------------
// Scatter-add COO weights directly into bf16 W (packed-bf16 atomic add).
// Duplicates still sum (coalesce semantics). mask is int32 on device (R1).
// ---------------------------------------------------------------------------
__global__ __launch_bounds__(256) void scatter_bf16(
    const float* __restrict__ w, const int* __restrict__ rows,
    const int* __restrict__ cols, const int* __restrict__ mask,
    unsigned* __restrict__ Wpk, int nnz) {
  int i = blockIdx.x * 256 + threadIdx.x;
  if (i >= nnz) return;
  if (mask[i] == 0) return;
  const unsigned h = f32_to_bf16_rne(w[i]);
  const size_t e = (size_t)rows[i] * IN_F + cols[i];
  const unsigned data = (e & 1) ? (h << 16) : h;
  unsigned* p = Wpk + (e >> 1);
  asm volatile("global_atomic_pk_add_bf16 %0, %1, off"
               :: "v"(p), "v"(data) : "memory");
}

// ---------------------------------------------------------------------------
// R11: K-PARITY 256x256 bf16 GEMM, C = A @ Bm^T.
// Cycle audit of R10 (per CU): MFMA 159K cy + LDS-read 144K cy ~= measured
// 278K -> pipes run nearly serial under barrier lockstep. Fix the LDS TERM:
// waves re-roled (wm,wn,wk)=2x2x2; each wave owns a 128x128 output over HALF
// the K (wk picks the ks-half of each K64 tile). Bytes/flop drops 33%
// (LDS 144K->96K cy) and 32x32x16 MFMA (2382 TF ubench) cuts MFMA to 139K.
// acc = 4x4 frags of 32x32 = 256 VGPR -> __launch_bounds__(512,1).
// LDS memory map, staging macro, and XOR swizzle are R4-verified, UNCHANGED.
// 4 phases per 2 K64-tiles; each phase: 8 ds_read_b128 + 16 MFMA.
// Ledger: P1 reads T0.kwin0, stages tile 2i+1 -> buf1 (8 loads)
//         P2 reads T0.kwin1, VM(0)  [2i+1 landed; issued ~2 phases ago]
//         P3 reads T1.kwin0, stages tile 2i+2 -> buf0
//         P4 reads T1.kwin1, VM(0)  [2i+2 landed before next P1]
// Regions: buf0 (tile 2i) read P1+P2 (both halves, split by wk), dead after
// P2, overwritten P3 (>=1 BAR after). buf1 read P3+P4, overwritten next-P1.
// Epilogue: wk1 adds its partial into wk0 via LDS (2 rounds x 128KB), then
// wk0 stores. Main-loop LDS fully drained (VM(0)@P2 of peeled iter) first.
// A/B frag mapping (by analogy with R2-verified 16x16): A row=lane&31,
// k=8*(lane>>5)+e; B n=lane&31, same k. C/D (m74/m101-verified): col=lane&31,
// row=(reg&3)+8*(reg>>2)+4*(lane>>5).
// ---------------------------------------------------------------------------
#define A0_B 0
#define B0_B 32768
#define A1_B 65536
#define B1_B 98304
#define HALF 16384

#define STAGE(Xg, kpos, ldsbase) do {                                          \
  __builtin_amdgcn_global_load_lds(                                            \
    (const __attribute__((address_space(1))) void*)((Xg) + (size_t)srow * 4096 + (kpos) + schunk), \
    (__attribute__((address_space(3))) void*)(lds + (ldsbase) + tid * 16), 16, 0, 0); \
  __builtin_amdgcn_global_load_lds(                                            \
    (const __attribute__((address_space(1))) void*)((Xg) + (size_t)(srow + 128) * 4096 + (kpos) + schunk), \
    (__attribute__((address_space(3))) void*)(lds + (ldsbase) + 8192 + tid * 16), 16, 0, 0); \
} while (0)

// 8 ds_read_b128: 4 A row-blocks + 4 B col-blocks for k-window kw (literal!)
#define RD8(ab, bb, kw) do {                                                   \
  _Pragma("unroll")                                                            \
  for (int q = 0; q < 4; ++q) {                                                \
    a[q] = *(const bf16x8*)(lds + (ab) + wkoff + offA[kw][q]);                 \
    b[q] = *(const bf16x8*)(lds + (bb) + wkoff + offB[kw][q]);                 \
  }                                                                            \
} while (0)

#define MM16() do {                                                            \
  _Pragma("unroll")                                                            \
  for (int mi = 0; mi < 4; ++mi)                                               \
    _Pragma("unroll")                                                          \
    for (int ni = 0; ni < 4; ++ni)                                             \
      acc[mi][ni] = __builtin_amdgcn_mfma_f32_32x32x16_bf16(                   \
          a[mi], b[ni], acc[mi][ni], 0, 0, 0);                                 \
} while (0)

#define BAR()   __builtin_amdgcn_s_barrier()
#define LGKM0() do { asm volatile("s_waitcnt lgkmcnt(0)" ::: "memory");        \
                     __builtin_amdgcn_sched_barrier(0); } while (0)
#define VM(n)   asm volatile("s_waitcnt vmcnt(" #n ")" ::: "memory")
#define PRIO1() __builtin_amdgcn_s_setprio(1)
#define PRIO0() __builtin_amdgcn_s_setprio(0)

__global__ __launch_bounds__(512, 1) void gemm_kp(
    const bf16_t* __restrict__ Amat, const bf16_t* __restrict__ Bmat,
    float* __restrict__ C) {
  __shared__ __align__(16) char lds[131072];

  const int tid  = threadIdx.x;
  const int lane = tid & 63;
  const int wave = tid >> 6;
  const int wk   = wave & 1;         // K-parity: which ks-half this wave eats
  const int wn   = (wave >> 1) & 1;  // N half (0..1)
  const int wm   = wave >> 2;        // M half (0..1)
  const int wkoff = wk * HALF;

  // T1: XCD-aware swizzle; 256 blocks % 8 == 0 -> bijective
  const int sbid = (blockIdx.x & 7) * 32 + (blockIdx.x >> 3);
  const int bm   = sbid >> 4;
  const int bn   = sbid & 15;

  const int l31  = lane & 31;
  const int half = lane >> 5;        // k-subchunk within K16 window

  // ds_read byte offsets within a ks-half [256 rows][32 k] region.
  // slot c = kw*2 + half (4 x 16B slots per 64B row); phys = c ^ ((row>>1)&3)
  // (R4-verified decorrelated swizzle, 0 conflicts).
  int offA[2][4], offB[2][4];
#pragma unroll
  for (int kw = 0; kw < 2; ++kw)
#pragma unroll
    for (int q = 0; q < 4; ++q) {
      const int c = kw * 2 + half;
      const int rA = wm * 128 + q * 32 + l31;
      const int rB = wn * 128 + q * 32 + l31;
      offA[kw][q] = rA * 64 + ((c ^ ((rA >> 1) & 3)) << 4);
      offB[kw][q] = rB * 64 + ((c ^ ((rB >> 1) & 3)) << 4);
    }

  // staging: write-side inverse of the read swizzle (unchanged from R4)
  const int srow   = tid >> 2;
  const int schunk = ((tid & 3) ^ ((srow >> 1) & 3)) * 8;
  const bf16_t* Ag = Amat + (size_t)bm * 256 * 4096;
  const bf16_t* Bg = Bmat + (size_t)bn * 256 * 4096;

  f32x16 acc[4][4] = {};
  bf16x8 a[4], b[4];

  // ---- prologue: stage tile 0 -> buf0 (8 loads), drain, barrier
  STAGE(Ag, 0,  A0_B);
  STAGE(Ag, 32, A0_B + HALF);
  STAGE(Bg, 0,  B0_B);
  STAGE(Bg, 32, B0_B + HALF);
  VM(0);
  BAR();

#pragma unroll 1
  for (int i = 0; i < 31; ++i) {
    const int k1 = (2 * i + 1) * 64;
    const int k2 = (2 * i + 2) * 64;
    // P1: tile 2i kwin0 | stage tile 2i+1 -> buf1
    RD8(A0_B, B0_B, 0);
    STAGE(Ag, k1, A1_B);  STAGE(Ag, k1 + 32, A1_B + HALF);
    STAGE(Bg, k1, B1_B);  STAGE(Bg, k1 + 32, B1_B + HALF);
    BAR(); LGKM0(); PRIO1(); MM16(); PRIO0(); BAR();
    // P2: tile 2i kwin1 | drain buf1 loads (issued ~2 phases ago)
    RD8(A0_B, B0_B, 1);
    BAR(); LGKM0(); PRIO1(); MM16(); PRIO0(); VM(0); BAR();
    // P3: tile 2i+1 kwin0 | stage tile 2i+2 -> buf0
    RD8(A1_B, B1_B, 0);
    STAGE(Ag, k2, A0_B);  STAGE(Ag, k2 + 32, A0_B + HALF);
    STAGE(Bg, k2, B0_B);  STAGE(Bg, k2 + 32, B0_B + HALF);
    BAR(); LGKM0(); PRIO1(); MM16(); PRIO0(); BAR();
    // P4: tile 2i+1 kwin1 | drain buf0 loads
    RD8(A1_B, B1_B, 1);
    BAR(); LGKM0(); PRIO1(); MM16(); PRIO0(); VM(0); BAR();
  }

  // ---- peeled final pair (tiles 62 in buf0, 63 in buf1)
  RD8(A0_B, B0_B, 0);
  STAGE(Ag, 4032, A1_B);  STAGE(Ag, 4064, A1_B + HALF);
  STAGE(Bg, 4032, B1_B);  STAGE(Bg, 4064, B1_B + HALF);
  BAR(); LGKM0(); PRIO1(); MM16(); PRIO0(); BAR();
  RD8(A0_B, B0_B, 1);
  BAR(); LGKM0(); PRIO1(); MM16(); PRIO0(); VM(0); BAR();  // all VMEM drained
  RD8(A1_B, B1_B, 0);
  BAR(); LGKM0(); PRIO1(); MM16(); PRIO0(); BAR();
  RD8(A1_B, B1_B, 1);
  BAR(); LGKM0(); PRIO1(); MM16(); PRIO0();

  // ---- cross-wave K-reduction: wk1 partials -> wk0, via LDS (2 rounds)
  __syncthreads();
#pragma unroll 1
  for (int r = 0; r < 2; ++r) {
    if (wm == r && wk == 1) {
#pragma unroll
      for (int mi = 0; mi < 4; ++mi)
#pragma unroll
        for (int ni = 0; ni < 4; ++ni)
#pragma unroll
          for (int c = 0; c < 4; ++c) {
            f32x4 t;
            t[0] = acc[mi][ni][4 * c + 0];
            t[1] = acc[mi][ni][4 * c + 1];
            t[2] = acc[mi][ni][4 * c + 2];
            t[3] = acc[mi][ni][4 * c + 3];
            *(f32x4*)(lds + wn * 65536 + ((mi * 4 + ni) * 4 + c) * 1024 +
                      lane * 16) = t;
          }
    }
    __syncthreads();
    if (wm == r && wk == 0) {
#pragma unroll
      for (int mi = 0; mi < 4; ++mi)
#pragma unroll
        for (int ni = 0; ni < 4; ++ni)
#pragma unroll
          for (int c = 0; c < 4; ++c) {
            f32x4 t = *(const f32x4*)(lds + wn * 65536 +
                                      ((mi * 4 + ni) * 4 + c) * 1024 +
                                      lane * 16);
            acc[mi][ni][4 * c + 0] += t[0];
            acc[mi][ni][4 * c + 1] += t[1];
            acc[mi][ni][4 * c + 2] += t[2];
            acc[mi][ni][4 * c + 3] += t[3];
          }
    }
    __syncthreads();
  }

  // ---- C write by wk0 waves (32x32 D layout: col=lane&31,
  // row=(reg&3)+8*(reg>>2)+4*(lane>>5))
  if (wk == 0) {
#pragma unroll
    for (int mi = 0; mi < 4; ++mi)
#pragma unroll
      for (int ni = 0; ni < 4; ++ni) {
        const int rbase = bm * 256 + wm * 128 + mi * 32 + 4 * half;
        const int col   = bn * 256 + wn * 128 + ni * 32 + l31;
#pragma unroll
        for (int reg = 0; reg < 16; ++reg) {
          const int row = rbase + (reg & 3) + 8 * (reg >> 2);
          C[(size_t)row * 4096 + col] = acc[mi][ni][reg];
        }
      }
  }
}

// ---------------------------------------------------------------------------
extern "C" void kernel_launch(void* const* d_in, const int* in_sizes, int n_in,
                              void* d_out, int out_size, void* d_ws, size_t ws_size,
                              hipStream_t stream) {
  const float* x     = (const float*)d_in[0];
  const float* wvals = (const float*)d_in[1];
  const int*   idx   = (const int*)d_in[2];   // (2, nnz): rows then cols
  const int*   mk    = (const int*)d_in[3];   // bool -> int32 on device (R1)
  const int    nnz   = in_sizes[1];

  // ws: [0,32MB) = W bf16, [32MB,64MB) = x bf16.
  bf16_t* Wbf = (bf16_t*)d_ws;
  bf16_t* xbf = (bf16_t*)((char*)d_ws + (size_t)OUT_F * IN_F * sizeof(bf16_t));

  const size_t needed = (size_t)OUT_F * IN_F * 2 + (size_t)BATCH * IN_F * 2;
  if (ws_size < needed) return;

  // 1. fused: zero bf16 W + convert x -> bf16 (high occupancy)
  init_zero_cvtx<<<2048, 256, 0, stream>>>(
      (uint4*)Wbf, (const float4*)x, (uint4*)xbf);

  // 2. scatter-add active weights directly in bf16 (packed atomic)
  scatter_bf16<<<(nnz + 255) / 256, 256, 0, stream>>>(
      wvals, idx, idx + nnz, mk, (unsigned*)Wbf, nnz);

  // 3. y = x @ W^T (K-parity 32x32x16 structure)
  gemm_kp<<<256, 512, 0, stream>>>(xbf, Wbf, (float*)d_out);
}

// Round 12
// 208.279 us; speedup vs baseline: 9.2819x; 9.2819x over previous
//
#include <hip/hip_runtime.h>
#include <cstdint>
#include <cstddef>

// Problem constants (SparseLinear: B=4096, IN=4096, OUT=4096, NNZ=1677722)
#define IN_F  4096
#define OUT_F 4096
#define BATCH 4096

typedef __bf16 bf16_t;
typedef __bf16 bf16x8 __attribute__((ext_vector_type(8)));
typedef float  f32x4  __attribute__((ext_vector_type(4)));

// ---------------------------------------------------------------------------
// f32 -> bf16 round-to-nearest-even (bit trick, deterministic)
// ---------------------------------------------------------------------------
__device__ __forceinline__ unsigned short f32_to_bf16_rne(float f) {
  union { float f; unsigned int u; } v;
  v.f = f;
  unsigned int u = v.u;
  return (unsigned short)((u + 0x7FFFu + ((u >> 16) & 1u)) >> 16);
}

__device__ __forceinline__ uint4 cvt8(float4 a, float4 b) {
  uint4 o;
  o.x = (unsigned)f32_to_bf16_rne(a.x) | ((unsigned)f32_to_bf16_rne(a.y) << 16);
  o.y = (unsigned)f32_to_bf16_rne(a.z) | ((unsigned)f32_to_bf16_rne(a.w) << 16);
  o.z = (unsigned)f32_to_bf16_rne(b.x) | ((unsigned)f32_to_bf16_rne(b.y) << 16);
  o.w = (unsigned)f32_to_bf16_rne(b.z) | ((unsigned)f32_to_bf16_rne(b.w) << 16);
  return o;
}

// ---------------------------------------------------------------------------
// Fused: scatter COO weights into bf16 W (packed atomic) + cvt x -> bf16.
// The two works are independent (Wbf vs xbf); interleaving them in one
// grid-stride dispatch overlaps latency-bound atomics with BW-bound cvt
// (R9 lesson kept: high occupancy, no GEMM-sized blocks).
// Zero-W precedes this dispatch via hipMemsetAsync (stream-ordered).
// mask is int32 on device (R1: bool -> int32). Duplicates sum (coalesce).
// ---------------------------------------------------------------------------
#define XUNITS ((BATCH * IN_F) / 8)   // 8-elem units of x (2097152)

__global__ __launch_bounds__(256) void scatter_cvtx(
    const float* __restrict__ w, const int* __restrict__ rows,
    const int* __restrict__ cols, const int* __restrict__ mask,
    unsigned* __restrict__ Wpk, int nnz,
    const float4* __restrict__ xin, uint4* __restrict__ xbf) {
  const int total = XUNITS + nnz;
  for (int u = blockIdx.x * 256 + threadIdx.x; u < total;
       u += gridDim.x * 256) {
    if (u < XUNITS) {
      xbf[u] = cvt8(xin[2 * u], xin[2 * u + 1]);
    } else {
      const int i = u - XUNITS;
      if (mask[i] != 0) {
        const unsigned h = f32_to_bf16_rne(w[i]);
        const size_t e = (size_t)rows[i] * IN_F + cols[i];
        const unsigned data = (e & 1) ? (h << 16) : h;
        unsigned* p = Wpk + (e >> 1);
        asm volatile("global_atomic_pk_add_bf16 %0, %1, off"
                     :: "v"(p), "v"(data) : "memory");
      }
    }
  }
}

// ---------------------------------------------------------------------------
// 256x256 8-phase bf16 GEMM, C = A @ Bm^T (row-major [4096][4096]).
// R10-EXACT (best measured: 116.0us, MfmaUtil 50, conflicts 0). Frozen:
// R5 deep-vmcnt / R6 4-phase / R8 readahead = flat-to-negative; R11 K-parity
// 32x32 = VGPR spill catastrophe (256-reg acc -> scratch, 9.5GB traffic).
// Ceiling arithmetic (R9/R10): per-CU MFMA ~159K cy + LDS-read ~144K cy run
// near-serial under barrier lockstep at 1 block/CU; this structure's floor.
// ---------------------------------------------------------------------------
#define A0_B 0
#define B0_B 32768
#define A1_B 65536
#define B1_B 98304
#define HALF 16384

#define STAGE(Xg, kpos, ldsbase) do {                                          \
  __builtin_amdgcn_global_load_lds(                                            \
    (const __attribute__((address_space(1))) void*)((Xg) + (size_t)srow * 4096 + (kpos) + schunk), \
    (__attribute__((address_space(3))) void*)(lds + (ldsbase) + tid * 16), 16, 0, 0); \
  __builtin_amdgcn_global_load_lds(                                            \
    (const __attribute__((address_space(1))) void*)((Xg) + (size_t)(srow + 128) * 4096 + (kpos) + schunk), \
    (__attribute__((address_space(3))) void*)(lds + (ldsbase) + 8192 + tid * 16), 16, 0, 0); \
} while (0)

#define LDA4(base, mh) do {                                                    \
  a0 = *(const bf16x8*)(lds + (base) + offA[mh][0]);                           \
  a1 = *(const bf16x8*)(lds + (base) + offA[mh][1]);                           \
  a2 = *(const bf16x8*)(lds + (base) + offA[mh][2]);                           \
  a3 = *(const bf16x8*)(lds + (base) + offA[mh][3]);                           \
} while (0)

#define LDB4(base) do {                                                        \
  b0 = *(const bf16x8*)(lds + (base) + offB[0]);                               \
  b1 = *(const bf16x8*)(lds + (base) + offB[1]);                               \
  b2 = *(const bf16x8*)(lds + (base) + offB[2]);                               \
  b3 = *(const bf16x8*)(lds + (base) + offB[3]);                               \
} while (0)

#define MFMA16(mh) do {                                                        \
  acc[(mh)*4+0][0] = __builtin_amdgcn_mfma_f32_16x16x32_bf16(a0, b0, acc[(mh)*4+0][0], 0, 0, 0); \
  acc[(mh)*4+0][1] = __builtin_amdgcn_mfma_f32_16x16x32_bf16(a0, b1, acc[(mh)*4+0][1], 0, 0, 0); \
  acc[(mh)*4+0][2] = __builtin_amdgcn_mfma_f32_16x16x32_bf16(a0, b2, acc[(mh)*4+0][2], 0, 0, 0); \
  acc[(mh)*4+0][3] = __builtin_amdgcn_mfma_f32_16x16x32_bf16(a0, b3, acc[(mh)*4+0][3], 0, 0, 0); \
  acc[(mh)*4+1][0] = __builtin_amdgcn_mfma_f32_16x16x32_bf16(a1, b0, acc[(mh)*4+1][0], 0, 0, 0); \
  acc[(mh)*4+1][1] = __builtin_amdgcn_mfma_f32_16x16x32_bf16(a1, b1, acc[(mh)*4+1][1], 0, 0, 0); \
  acc[(mh)*4+1][2] = __builtin_amdgcn_mfma_f32_16x16x32_bf16(a1, b2, acc[(mh)*4+1][2], 0, 0, 0); \
  acc[(mh)*4+1][3] = __builtin_amdgcn_mfma_f32_16x16x32_bf16(a1, b3, acc[(mh)*4+1][3], 0, 0, 0); \
  acc[(mh)*4+2][0] = __builtin_amdgcn_mfma_f32_16x16x32_bf16(a2, b0, acc[(mh)*4+2][0], 0, 0, 0); \
  acc[(mh)*4+2][1] = __builtin_amdgcn_mfma_f32_16x16x32_bf16(a2, b1, acc[(mh)*4+2][1], 0, 0, 0); \
  acc[(mh)*4+2][2] = __builtin_amdgcn_mfma_f32_16x16x32_bf16(a2, b2, acc[(mh)*4+2][2], 0, 0, 0); \
  acc[(mh)*4+2][3] = __builtin_amdgcn_mfma_f32_16x16x32_bf16(a2, b3, acc[(mh)*4+2][3], 0, 0, 0); \
  acc[(mh)*4+3][0] = __builtin_amdgcn_mfma_f32_16x16x32_bf16(a3, b0, acc[(mh)*4+3][0], 0, 0, 0); \
  acc[(mh)*4+3][1] = __builtin_amdgcn_mfma_f32_16x16x32_bf16(a3, b1, acc[(mh)*4+3][1], 0, 0, 0); \
  acc[(mh)*4+3][2] = __builtin_amdgcn_mfma_f32_16x16x32_bf16(a3, b2, acc[(mh)*4+3][2], 0, 0, 0); \
  acc[(mh)*4+3][3] = __builtin_amdgcn_mfma_f32_16x16x32_bf16(a3, b3, acc[(mh)*4+3][3], 0, 0, 0); \
} while (0)

#define BAR()   __builtin_amdgcn_s_barrier()
#define LGKM0() do { asm volatile("s_waitcnt lgkmcnt(0)" ::: "memory");        \
                     __builtin_amdgcn_sched_barrier(0); } while (0)
#define VM(n)   asm volatile("s_waitcnt vmcnt(" #n ")" ::: "memory")
#define PRIO1() __builtin_amdgcn_s_setprio(1)
#define PRIO0() __builtin_amdgcn_s_setprio(0)

__global__ __launch_bounds__(512, 2) void gemm_bt_8ph(
    const bf16_t* __restrict__ A, const bf16_t* __restrict__ Bm,
    float* __restrict__ C) {
  __shared__ __align__(16) char lds[131072];

  const int tid  = threadIdx.x;
  const int lane = tid & 63;
  const int wave = tid >> 6;
  const int wm   = wave >> 2;  // 0..1  (M half of block)
  const int wn   = wave & 3;   // 0..3  (N quarter of block)

  // T1: XCD-aware swizzle; 256 blocks % 8 == 0 -> bijective
  const int sbid = (blockIdx.x & 7) * 32 + (blockIdx.x >> 3);
  const int bm   = sbid >> 4;
  const int bn   = sbid & 15;

  const int frow = lane & 15;
  const int c16  = (lane >> 4) * 16;  // 16B chunk within 64B row

  // ds_read byte offsets within a ks-half [256][32] region (T2-swizzled,
  // decorrelated: XOR with row bits 1-2; R4-verified 0 conflicts)
  int offA[2][4], offB[4];
#pragma unroll
  for (int mh = 0; mh < 2; ++mh)
#pragma unroll
    for (int mi = 0; mi < 4; ++mi) {
      int r = wm * 128 + mh * 64 + mi * 16 + frow;
      offA[mh][mi] = r * 64 + (c16 ^ (((r >> 1) & 3) << 4));
    }
#pragma unroll
  for (int ni = 0; ni < 4; ++ni) {
    int r = wn * 64 + ni * 16 + frow;
    offB[ni] = r * 64 + (c16 ^ (((r >> 1) & 3) << 4));
  }

  // staging: write-side inverse of the read swizzle ((srow+128) keeps the
  // same ((row>>1)&3): bit7 is stripped by &3)
  const int srow   = tid >> 2;
  const int schunk = ((tid & 3) ^ ((srow >> 1) & 3)) * 8;
  const bf16_t* Ag = A  + (size_t)bm * 256 * 4096;
  const bf16_t* Bg = Bm + (size_t)bn * 256 * 4096;

  f32x4 acc[8][4] = {};
  bf16x8 a0, a1, a2, a3, b0, b1, b2, b3;

  // ---- prologue: tile0 (full) + tile1 ks0; drain tile0, keep tile1 in flight
  STAGE(Ag, 0,  A0_B);
  STAGE(Bg, 0,  B0_B);
  STAGE(Ag, 32, A0_B + HALF);
  STAGE(Bg, 32, B0_B + HALF);
  STAGE(Ag, 64, A1_B);
  STAGE(Bg, 64, B1_B);
  VM(4);
  BAR();

  int kb = 0;
#pragma unroll 1
  for (int i = 0; i < 31; ++i, kb += 128) {
    // ph1: tile t ks0 mh0
    LDA4(A0_B, 0); LDB4(B0_B);
    STAGE(Ag, kb + 96, A1_B + HALF);
    BAR(); LGKM0(); PRIO1(); MFMA16(0); PRIO0(); BAR();
    // ph2: tile t ks0 mh1
    LDA4(A0_B, 1);
    STAGE(Bg, kb + 96, B1_B + HALF);
    BAR(); LGKM0(); PRIO1(); MFMA16(1); PRIO0(); BAR();
    // ph3: tile t ks1 mh0
    LDA4(A0_B + HALF, 0); LDB4(B0_B + HALF);
    STAGE(Ag, kb + 128, A0_B);
    BAR(); LGKM0(); PRIO1(); MFMA16(0); PRIO0(); BAR();
    // ph4: tile t ks1 mh1   [counted drain: tile t+1 fully landed]
    LDA4(A0_B + HALF, 1);
    STAGE(Bg, kb + 128, B0_B);
    BAR(); LGKM0(); PRIO1(); MFMA16(1); PRIO0(); VM(4); BAR();
    // ph5: tile t+1 ks0 mh0
    LDA4(A1_B, 0); LDB4(B1_B);
    STAGE(Ag, kb + 160, A0_B + HALF);
    BAR(); LGKM0(); PRIO1(); MFMA16(0); PRIO0(); BAR();
    // ph6: tile t+1 ks0 mh1
    LDA4(A1_B, 1);
    STAGE(Bg, kb + 160, B0_B + HALF);
    BAR(); LGKM0(); PRIO1(); MFMA16(1); PRIO0(); BAR();
    // ph7: tile t+1 ks1 mh0
    LDA4(A1_B + HALF, 0); LDB4(B1_B + HALF);
    STAGE(Ag, kb + 192, A1_B);
    BAR(); LGKM0(); PRIO1(); MFMA16(0); PRIO0(); BAR();
    // ph8: tile t+1 ks1 mh1  [counted drain: tile t+2 fully landed]
    LDA4(A1_B + HALF, 1);
    STAGE(Bg, kb + 192, B1_B);
    BAR(); LGKM0(); PRIO1(); MFMA16(1); PRIO0(); VM(4); BAR();
  }

  // ---- epilogue: tiles 62 (buf0) and 63 (buf1); kb == 3968
  LDA4(A0_B, 0); LDB4(B0_B);
  STAGE(Ag, kb + 96, A1_B + HALF);          // A(63)ks1
  BAR(); LGKM0(); PRIO1(); MFMA16(0); PRIO0(); BAR();
  LDA4(A0_B, 1);
  STAGE(Bg, kb + 96, B1_B + HALF);          // B(63)ks1
  BAR(); LGKM0(); PRIO1(); MFMA16(1); PRIO0(); BAR();
  LDA4(A0_B + HALF, 0); LDB4(B0_B + HALF);
  BAR(); LGKM0(); PRIO1(); MFMA16(0); PRIO0(); BAR();
  LDA4(A0_B + HALF, 1);
  BAR(); LGKM0(); PRIO1(); MFMA16(1); PRIO0(); VM(0); BAR();
  LDA4(A1_B, 0); LDB4(B1_B);
  BAR(); LGKM0(); PRIO1(); MFMA16(0); PRIO0(); BAR();
  LDA4(A1_B, 1);
  BAR(); LGKM0(); PRIO1(); MFMA16(1); PRIO0(); BAR();
  LDA4(A1_B + HALF, 0); LDB4(B1_B + HALF);
  BAR(); LGKM0(); PRIO1(); MFMA16(0); PRIO0(); BAR();
  LDA4(A1_B + HALF, 1);
  LGKM0(); PRIO1(); MFMA16(1); PRIO0();

  // ---- C write (D layout: col = lane&15, row = (lane>>4)*4 + jj)
#pragma unroll
  for (int mh = 0; mh < 2; ++mh)
#pragma unroll
    for (int mi = 0; mi < 4; ++mi)
#pragma unroll
      for (int ni = 0; ni < 4; ++ni) {
        const int row = bm * 256 + wm * 128 + mh * 64 + mi * 16 + (lane >> 4) * 4;
        const int col = bn * 256 + wn * 64 + ni * 16 + frow;
#pragma unroll
        for (int jj = 0; jj < 4; ++jj)
          C[(size_t)(row + jj) * 4096 + col] = acc[mh * 4 + mi][ni][jj];
      }
}

// ---------------------------------------------------------------------------
extern "C" void kernel_launch(void* const* d_in, const int* in_sizes, int n_in,
                              void* d_out, int out_size, void* d_ws, size_t ws_size,
                              hipStream_t stream) {
  const float* x     = (const float*)d_in[0];
  const float* wvals = (const float*)d_in[1];
  const int*   idx   = (const int*)d_in[2];   // (2, nnz): rows then cols
  const int*   mk    = (const int*)d_in[3];   // bool -> int32 on device (R1)
  const int    nnz   = in_sizes[1];

  // ws: [0,32MB) = W bf16, [32MB,64MB) = x bf16.
  bf16_t* Wbf = (bf16_t*)d_ws;
  bf16_t* xbf = (bf16_t*)((char*)d_ws + (size_t)OUT_F * IN_F * sizeof(bf16_t));

  const size_t needed = (size_t)OUT_F * IN_F * 2 + (size_t)BATCH * IN_F * 2;
  if (ws_size < needed) return;

  // 1. zero bf16 W via DMA memset (stream-ordered before scatter)
  hipMemsetAsync(Wbf, 0, (size_t)OUT_F * IN_F * sizeof(bf16_t), stream);

  // 2. fused: scatter (latency-bound atomics) + cvt x (BW-bound) overlap
  scatter_cvtx<<<2048, 256, 0, stream>>>(
      wvals, idx, idx + nnz, mk, (unsigned*)Wbf, nnz,
      (const float4*)x, (uint4*)xbf);

  // 3. y = x @ W^T (R10-exact 8-phase schedule)
  gemm_bt_8ph<<<256, 512, 0, stream>>>(xbf, Wbf, (float*)d_out);
}

// Round 13
// 203.557 us; speedup vs baseline: 9.4972x; 1.0232x over previous
//
#include <hip/hip_runtime.h>
#include <cstdint>
#include <cstddef>

// Problem constants (SparseLinear: B=4096, IN=4096, OUT=4096, NNZ=1677722)
#define IN_F  4096
#define OUT_F 4096
#define BATCH 4096

typedef __bf16 bf16_t;
typedef __bf16 bf16x8 __attribute__((ext_vector_type(8)));
typedef float  f32x4  __attribute__((ext_vector_type(4)));

// ---------------------------------------------------------------------------
// f32 -> bf16 round-to-nearest-even (bit trick, deterministic)
// ---------------------------------------------------------------------------
__device__ __forceinline__ unsigned short f32_to_bf16_rne(float f) {
  union { float f; unsigned int u; } v;
  v.f = f;
  unsigned int u = v.u;
  return (unsigned short)((u + 0x7FFFu + ((u >> 16) & 1u)) >> 16);
}

__device__ __forceinline__ uint4 cvt8(float4 a, float4 b) {
  uint4 o;
  o.x = (unsigned)f32_to_bf16_rne(a.x) | ((unsigned)f32_to_bf16_rne(a.y) << 16);
  o.y = (unsigned)f32_to_bf16_rne(a.z) | ((unsigned)f32_to_bf16_rne(a.w) << 16);
  o.z = (unsigned)f32_to_bf16_rne(b.x) | ((unsigned)f32_to_bf16_rne(b.y) << 16);
  o.w = (unsigned)f32_to_bf16_rne(b.z) | ((unsigned)f32_to_bf16_rne(b.w) << 16);
  return o;
}

// ---------------------------------------------------------------------------
// Fused: scatter COO weights into bf16 W (packed atomic) + cvt x -> bf16.
// Tail is scatter-dominated (~70us of device-scope atomics; R6/R10/R12 all
// ~92us regardless of structure — fabric-limited, frozen). mask is int32 on
// device (R1). Duplicates sum (coalesce semantics).
// ---------------------------------------------------------------------------
#define XUNITS ((BATCH * IN_F) / 8)   // 8-elem units of x (2097152)

__global__ __launch_bounds__(256) void scatter_cvtx(
    const float* __restrict__ w, const int* __restrict__ rows,
    const int* __restrict__ cols, const int* __restrict__ mask,
    unsigned* __restrict__ Wpk, int nnz,
    const float4* __restrict__ xin, uint4* __restrict__ xbf) {
  const int total = XUNITS + nnz;
  for (int u = blockIdx.x * 256 + threadIdx.x; u < total;
       u += gridDim.x * 256) {
    if (u < XUNITS) {
      xbf[u] = cvt8(xin[2 * u], xin[2 * u + 1]);
    } else {
      const int i = u - XUNITS;
      if (mask[i] != 0) {
        const unsigned h = f32_to_bf16_rne(w[i]);
        const size_t e = (size_t)rows[i] * IN_F + cols[i];
        const unsigned data = (e & 1) ? (h << 16) : h;
        unsigned* p = Wpk + (e >> 1);
        asm volatile("global_atomic_pk_add_bf16 %0, %1, off"
                     :: "v"(p), "v"(data) : "memory");
      }
    }
  }
}

// ---------------------------------------------------------------------------
// R13: QUADRANT/B-HOIST 256x256 bf16 GEMM, C = A @ Bm^T.
// m201's remaining structural delta vs R4: phases = C-quadrants; B-frags for
// the whole K64 tile are ds_read ONCE (ph1/ph5, 8 b128) and persist in regs
// across 4 phases; later phases read only 4 A-frags -> per-phase lgkm
// exposure drops from 8-12 reads to 4, and B ds_read count halves.
// Unchanged (R4-verified): LDS [ks(2)][256][32] per buffer, decorrelated XOR
// swizzle (0 conflicts), STAGE macro, T1 XCD swizzle, T5 setprio.
// Ledger (iter i, t=2i, kb=128i; reads: t from A0/B0 ph1-4, t+1 from A1/B1
// ph5-8; B0 read ph1 only, B1 ph5 only, A0 q3 last at ph4, A1 q3 at ph8):
//   stages: ph1 A1ks0<-A(t+1), ph2 A1ks1<-A(t+1)   [A1 dead after prev ph8]
//           ph3 B0ks0<-B(t+2), ph4 B0ks1<-B(t+2)   [B0 dead after ph1]
//           ph5 A0ks0<-A(t+2), ph6 A0ks1<-A(t+2)   [A0 dead after ph4]
//           ph7 B1ks0<-B(t+3), ph8 B1ks1<-B(t+3)   [B1 dead after ph5]
//   VM(4) end-ph4: outstanding = prev{7,8}+cur{1..4}=12, drains 8 oldest =
//     B1(prev7,8)+A1(cur1,2) == exactly ph5's reads. VM(4) end-ph8:
//     outstanding = cur{3..8}=12, drains cur{3,4,5,6} = B0+A0 == next ph1.
//   Prologue: A(0),B(0),B(1) = 12 loads, VM(4) leaves B(1) in flight
//     (steady-state invariant). Epilogue peel: no stages ph3-8, VM(0)@ph4.
// ---------------------------------------------------------------------------
#define A0_B 0
#define B0_B 32768
#define A1_B 65536
#define B1_B 98304
#define HALF 16384

#define STAGE(Xg, kpos, ldsbase) do {                                          \
  __builtin_amdgcn_global_load_lds(                                            \
    (const __attribute__((address_space(1))) void*)((Xg) + (size_t)srow * 4096 + (kpos) + schunk), \
    (__attribute__((address_space(3))) void*)(lds + (ldsbase) + tid * 16), 16, 0, 0); \
  __builtin_amdgcn_global_load_lds(                                            \
    (const __attribute__((address_space(1))) void*)((Xg) + (size_t)(srow + 128) * 4096 + (kpos) + schunk), \
    (__attribute__((address_space(3))) void*)(lds + (ldsbase) + 8192 + tid * 16), 16, 0, 0); \
} while (0)

// B for the whole K64 tile: 4 N-frags x 2 k-halves (8 x ds_read_b128)
#define RDB(base) do {                                                         \
  _Pragma("unroll")                                                            \
  for (int ni = 0; ni < 4; ++ni)                                               \
    _Pragma("unroll")                                                          \
    for (int kk = 0; kk < 2; ++kk)                                             \
      b[ni][kk] = *(const bf16x8*)(lds + (base) + kk * HALF + offB[ni]);       \
} while (0)

// A for one quadrant: 2 M-frags x 2 k-halves (4 x ds_read_b128)
#define RDA(base, q) do {                                                      \
  _Pragma("unroll")                                                            \
  for (int mi = 0; mi < 2; ++mi)                                               \
    _Pragma("unroll")                                                          \
    for (int kk = 0; kk < 2; ++kk)                                             \
      a[mi][kk] = *(const bf16x8*)(lds + (base) + kk * HALF + offA[q][mi]);    \
} while (0)

// One quadrant x K64: 2M x 4N x 2K = 16 MFMA (all indices compile-time)
#define MFMAQ(q) do {                                                          \
  _Pragma("unroll")                                                            \
  for (int mi = 0; mi < 2; ++mi)                                               \
    _Pragma("unroll")                                                          \
    for (int ni = 0; ni < 4; ++ni)                                             \
      _Pragma("unroll")                                                        \
      for (int kk = 0; kk < 2; ++kk)                                           \
        acc[2 * (q) + mi][ni] = __builtin_amdgcn_mfma_f32_16x16x32_bf16(       \
            a[mi][kk], b[ni][kk], acc[2 * (q) + mi][ni], 0, 0, 0);             \
} while (0)

#define BAR()   __builtin_amdgcn_s_barrier()
#define LGKM0() do { asm volatile("s_waitcnt lgkmcnt(0)" ::: "memory");        \
                     __builtin_amdgcn_sched_barrier(0); } while (0)
#define VM(n)   asm volatile("s_waitcnt vmcnt(" #n ")" ::: "memory")
#define PRIO1() __builtin_amdgcn_s_setprio(1)
#define PRIO0() __builtin_amdgcn_s_setprio(0)

__global__ __launch_bounds__(512, 2) void gemm_q(
    const bf16_t* __restrict__ A, const bf16_t* __restrict__ Bm,
    float* __restrict__ C) {
  __shared__ __align__(16) char lds[131072];

  const int tid  = threadIdx.x;
  const int lane = tid & 63;
  const int wave = tid >> 6;
  const int wm   = wave >> 2;  // 0..1  (M half of block)
  const int wn   = wave & 3;   // 0..3  (N quarter of block)

  // T1: XCD-aware swizzle; 256 blocks % 8 == 0 -> bijective
  const int sbid = (blockIdx.x & 7) * 32 + (blockIdx.x >> 3);
  const int bm   = sbid >> 4;
  const int bn   = sbid & 15;

  const int frow = lane & 15;
  const int c16  = (lane >> 4) * 16;  // 16B chunk within 64B row

  // ds_read byte offsets within a ks-half [256][32] region (R4-verified
  // decorrelated swizzle: slot ^ ((row>>1)&3), 0 conflicts)
  int offA[4][2], offB[4];
#pragma unroll
  for (int q = 0; q < 4; ++q)
#pragma unroll
    for (int mi = 0; mi < 2; ++mi) {
      int r = wm * 128 + q * 32 + mi * 16 + frow;
      offA[q][mi] = r * 64 + (c16 ^ (((r >> 1) & 3) << 4));
    }
#pragma unroll
  for (int ni = 0; ni < 4; ++ni) {
    int r = wn * 64 + ni * 16 + frow;
    offB[ni] = r * 64 + (c16 ^ (((r >> 1) & 3) << 4));
  }

  // staging: write-side inverse of the read swizzle ((srow+128) keeps the
  // same ((row>>1)&3): bit7 is stripped by &3)
  const int srow   = tid >> 2;
  const int schunk = ((tid & 3) ^ ((srow >> 1) & 3)) * 8;
  const bf16_t* Ag = A  + (size_t)bm * 256 * 4096;
  const bf16_t* Bg = Bm + (size_t)bn * 256 * 4096;

  f32x4 acc[8][4] = {};
  bf16x8 a[2][2], b[4][2];

  // ---- prologue: A(0), B(0), B(1); VM(4) leaves B(1) in flight
  STAGE(Ag, 0,  A0_B);
  STAGE(Ag, 32, A0_B + HALF);
  STAGE(Bg, 0,  B0_B);
  STAGE(Bg, 32, B0_B + HALF);
  STAGE(Bg, 64, B1_B);
  STAGE(Bg, 96, B1_B + HALF);
  VM(4);
  BAR();

  int kb = 0;
#pragma unroll 1
  for (int i = 0; i < 31; ++i, kb += 128) {
    // ph1: tile t q0 (B hoist: read all B(t) + A q0) | stage A(t+1)ks0
    RDB(B0_B); RDA(A0_B, 0);
    STAGE(Ag, kb + 64, A1_B);
    BAR(); LGKM0(); PRIO1(); MFMAQ(0); PRIO0(); BAR();
    // ph2: tile t q1 | stage A(t+1)ks1
    RDA(A0_B, 1);
    STAGE(Ag, kb + 96, A1_B + HALF);
    BAR(); LGKM0(); PRIO1(); MFMAQ(1); PRIO0(); BAR();
    // ph3: tile t q2 | stage B(t+2)ks0   [B0 dead since ph1]
    RDA(A0_B, 2);
    STAGE(Bg, kb + 128, B0_B);
    BAR(); LGKM0(); PRIO1(); MFMAQ(2); PRIO0(); BAR();
    // ph4: tile t q3 | stage B(t+2)ks1 | drain B1(prev)+A1(cur) for ph5
    RDA(A0_B, 3);
    STAGE(Bg, kb + 160, B0_B + HALF);
    BAR(); LGKM0(); PRIO1(); MFMAQ(3); PRIO0(); VM(4); BAR();
    // ph5: tile t+1 q0 (read all B(t+1) + A q0) | stage A(t+2)ks0
    RDB(B1_B); RDA(A1_B, 0);
    STAGE(Ag, kb + 128, A0_B);
    BAR(); LGKM0(); PRIO1(); MFMAQ(0); PRIO0(); BAR();
    // ph6: tile t+1 q1 | stage A(t+2)ks1
    RDA(A1_B, 1);
    STAGE(Ag, kb + 160, A0_B + HALF);
    BAR(); LGKM0(); PRIO1(); MFMAQ(1); PRIO0(); BAR();
    // ph7: tile t+1 q2 | stage B(t+3)ks0   [B1 dead since ph5]
    RDA(A1_B, 2);
    STAGE(Bg, kb + 192, B1_B);
    BAR(); LGKM0(); PRIO1(); MFMAQ(2); PRIO0(); BAR();
    // ph8: tile t+1 q3 | stage B(t+3)ks1 | drain B0+A0(t+2) for next ph1
    RDA(A1_B, 3);
    STAGE(Bg, kb + 224, B1_B + HALF);
    BAR(); LGKM0(); PRIO1(); MFMAQ(3); PRIO0(); VM(4); BAR();
  }

  // ---- epilogue peel (t=62,63; kb == 3968): stages only A(63), VM(0)@ph4
  RDB(B0_B); RDA(A0_B, 0);
  STAGE(Ag, 4032, A1_B);                     // A(63)ks0
  BAR(); LGKM0(); PRIO1(); MFMAQ(0); PRIO0(); BAR();
  RDA(A0_B, 1);
  STAGE(Ag, 4064, A1_B + HALF);              // A(63)ks1
  BAR(); LGKM0(); PRIO1(); MFMAQ(1); PRIO0(); BAR();
  RDA(A0_B, 2);
  BAR(); LGKM0(); PRIO1(); MFMAQ(2); PRIO0(); BAR();
  RDA(A0_B, 3);
  BAR(); LGKM0(); PRIO1(); MFMAQ(3); PRIO0(); VM(0); BAR();
  RDB(B1_B); RDA(A1_B, 0);
  BAR(); LGKM0(); PRIO1(); MFMAQ(0); PRIO0(); BAR();
  RDA(A1_B, 1);
  BAR(); LGKM0(); PRIO1(); MFMAQ(1); PRIO0(); BAR();
  RDA(A1_B, 2);
  BAR(); LGKM0(); PRIO1(); MFMAQ(2); PRIO0(); BAR();
  RDA(A1_B, 3);
  LGKM0(); PRIO1(); MFMAQ(3); PRIO0();

  // ---- C write (D layout: col = lane&15, row = (lane>>4)*4 + jj);
  // acc[m] <-> M-row block wm*128 + m*16 (m = 2q+mi), same as R4.
#pragma unroll
  for (int m = 0; m < 8; ++m)
#pragma unroll
    for (int ni = 0; ni < 4; ++ni) {
      const int row = bm * 256 + wm * 128 + m * 16 + (lane >> 4) * 4;
      const int col = bn * 256 + wn * 64 + ni * 16 + frow;
#pragma unroll
      for (int jj = 0; jj < 4; ++jj)
        C[(size_t)(row + jj) * 4096 + col] = acc[m][ni][jj];
    }
}

// ---------------------------------------------------------------------------
extern "C" void kernel_launch(void* const* d_in, const int* in_sizes, int n_in,
                              void* d_out, int out_size, void* d_ws, size_t ws_size,
                              hipStream_t stream) {
  const float* x     = (const float*)d_in[0];
  const float* wvals = (const float*)d_in[1];
  const int*   idx   = (const int*)d_in[2];   // (2, nnz): rows then cols
  const int*   mk    = (const int*)d_in[3];   // bool -> int32 on device (R1)
  const int    nnz   = in_sizes[1];

  // ws: [0,32MB) = W bf16, [32MB,64MB) = x bf16.
  bf16_t* Wbf = (bf16_t*)d_ws;
  bf16_t* xbf = (bf16_t*)((char*)d_ws + (size_t)OUT_F * IN_F * sizeof(bf16_t));

  const size_t needed = (size_t)OUT_F * IN_F * 2 + (size_t)BATCH * IN_F * 2;
  if (ws_size < needed) return;

  // 1. zero bf16 W via DMA memset (stream-ordered before scatter)
  hipMemsetAsync(Wbf, 0, (size_t)OUT_F * IN_F * sizeof(bf16_t), stream);

  // 2. fused: scatter (latency-bound atomics) + cvt x (BW-bound) overlap
  scatter_cvtx<<<2048, 256, 0, stream>>>(
      wvals, idx, idx + nnz, mk, (unsigned*)Wbf, nnz,
      (const float4*)x, (uint4*)xbf);

  // 3. y = x @ W^T (quadrant/B-hoist 8-phase schedule)
  gemm_q<<<256, 512, 0, stream>>>(xbf, Wbf, (float*)d_out);
}

// Round 14
// 199.501 us; speedup vs baseline: 9.6904x; 1.0203x over previous
//
#include <hip/hip_runtime.h>
#include <cstdint>
#include <cstddef>

// Problem constants (SparseLinear: B=4096, IN=4096, OUT=4096, NNZ=1677722)
#define IN_F  4096
#define OUT_F 4096
#define BATCH 4096

typedef __bf16 bf16_t;
typedef __bf16 bf16x8 __attribute__((ext_vector_type(8)));
typedef float  f32x4  __attribute__((ext_vector_type(4)));

// ---------------------------------------------------------------------------
// f32 -> bf16 round-to-nearest-even (bit trick, deterministic)
// ---------------------------------------------------------------------------
__device__ __forceinline__ unsigned short f32_to_bf16_rne(float f) {
  union { float f; unsigned int u; } v;
  v.f = f;
  unsigned int u = v.u;
  return (unsigned short)((u + 0x7FFFu + ((u >> 16) & 1u)) >> 16);
}

__device__ __forceinline__ uint4 cvt8(float4 a, float4 b) {
  uint4 o;
  o.x = (unsigned)f32_to_bf16_rne(a.x) | ((unsigned)f32_to_bf16_rne(a.y) << 16);
  o.y = (unsigned)f32_to_bf16_rne(a.z) | ((unsigned)f32_to_bf16_rne(a.w) << 16);
  o.z = (unsigned)f32_to_bf16_rne(b.x) | ((unsigned)f32_to_bf16_rne(b.y) << 16);
  o.w = (unsigned)f32_to_bf16_rne(b.z) | ((unsigned)f32_to_bf16_rne(b.w) << 16);
  return o;
}

// ---------------------------------------------------------------------------
// Fused: scatter COO weights into bf16 W (packed atomic) + cvt x -> bf16.
// R14: ATOMICS FIRST. The pk_add_bf16 atomics are no-return (fire-and-forget
// within the 63-slot vmcnt window); issuing them before the BW-bound cvt
// streaming lets the L3/fabric atomic pipe drain CONCURRENTLY with the HBM
// cvt traffic instead of serially after it (R12 order: cvt then atomics =
// ~18us + ~50us serial). mask is int32 on device (R1). Duplicates sum.
// ---------------------------------------------------------------------------
#define XUNITS ((BATCH * IN_F) / 8)   // 8-elem units of x (2097152)

__global__ __launch_bounds__(256) void scatter_cvtx(
    const float* __restrict__ w, const int* __restrict__ rows,
    const int* __restrict__ cols, const int* __restrict__ mask,
    unsigned* __restrict__ Wpk, int nnz,
    const float4* __restrict__ xin, uint4* __restrict__ xbf) {
  const int total = XUNITS + nnz;
  for (int u = blockIdx.x * 256 + threadIdx.x; u < total;
       u += gridDim.x * 256) {
    if (u < nnz) {                      // atomics first (fire-and-forget)
      if (mask[u] != 0) {
        const unsigned h = f32_to_bf16_rne(w[u]);
        const size_t e = (size_t)rows[u] * IN_F + cols[u];
        const unsigned data = (e & 1) ? (h << 16) : h;
        unsigned* p = Wpk + (e >> 1);
        asm volatile("global_atomic_pk_add_bf16 %0, %1, off"
                     :: "v"(p), "v"(data) : "memory");
      }
    } else {                            // BW-bound cvt streams under them
      const int i = u - nnz;
      xbf[i] = cvt8(xin[2 * i], xin[2 * i + 1]);
    }
  }
}

// ---------------------------------------------------------------------------
// R13 QUADRANT/B-HOIST 256x256 bf16 GEMM, C = A @ Bm^T — FROZEN.
// 116.2us, MfmaUtil 49.8, conflicts 0. Five schedule variants (R4 8-phase,
// R5 deep-vmcnt, R6 4-phase, R8 readahead, R13 quadrant) all land at the
// same ~116us / MfmaUtil~50 plateau: per-CU MFMA ~159K cy + LDS-read ~144K
// cy run near-serial under 1-block/CU barrier lockstep. R11 (32x32 frags,
// 128x128/wave) spilled catastrophically. This is the structure's floor at
// source level.
// ---------------------------------------------------------------------------
#define A0_B 0
#define B0_B 32768
#define A1_B 65536
#define B1_B 98304
#define HALF 16384

#define STAGE(Xg, kpos, ldsbase) do {                                          \
  __builtin_amdgcn_global_load_lds(                                            \
    (const __attribute__((address_space(1))) void*)((Xg) + (size_t)srow * 4096 + (kpos) + schunk), \
    (__attribute__((address_space(3))) void*)(lds + (ldsbase) + tid * 16), 16, 0, 0); \
  __builtin_amdgcn_global_load_lds(                                            \
    (const __attribute__((address_space(1))) void*)((Xg) + (size_t)(srow + 128) * 4096 + (kpos) + schunk), \
    (__attribute__((address_space(3))) void*)(lds + (ldsbase) + 8192 + tid * 16), 16, 0, 0); \
} while (0)

// B for the whole K64 tile: 4 N-frags x 2 k-halves (8 x ds_read_b128)
#define RDB(base) do {                                                         \
  _Pragma("unroll")                                                            \
  for (int ni = 0; ni < 4; ++ni)                                               \
    _Pragma("unroll")                                                          \
    for (int kk = 0; kk < 2; ++kk)                                             \
      b[ni][kk] = *(const bf16x8*)(lds + (base) + kk * HALF + offB[ni]);       \
} while (0)

// A for one quadrant: 2 M-frags x 2 k-halves (4 x ds_read_b128)
#define RDA(base, q) do {                                                      \
  _Pragma("unroll")                                                            \
  for (int mi = 0; mi < 2; ++mi)                                               \
    _Pragma("unroll")                                                          \
    for (int kk = 0; kk < 2; ++kk)                                             \
      a[mi][kk] = *(const bf16x8*)(lds + (base) + kk * HALF + offA[q][mi]);    \
} while (0)

// One quadrant x K64: 2M x 4N x 2K = 16 MFMA (all indices compile-time)
#define MFMAQ(q) do {                                                          \
  _Pragma("unroll")                                                            \
  for (int mi = 0; mi < 2; ++mi)                                               \
    _Pragma("unroll")                                                          \
    for (int ni = 0; ni < 4; ++ni)                                             \
      _Pragma("unroll")                                                        \
      for (int kk = 0; kk < 2; ++kk)                                           \
        acc[2 * (q) + mi][ni] = __builtin_amdgcn_mfma_f32_16x16x32_bf16(       \
            a[mi][kk], b[ni][kk], acc[2 * (q) + mi][ni], 0, 0, 0);             \
} while (0)

#define BAR()   __builtin_amdgcn_s_barrier()
#define LGKM0() do { asm volatile("s_waitcnt lgkmcnt(0)" ::: "memory");        \
                     __builtin_amdgcn_sched_barrier(0); } while (0)
#define VM(n)   asm volatile("s_waitcnt vmcnt(" #n ")" ::: "memory")
#define PRIO1() __builtin_amdgcn_s_setprio(1)
#define PRIO0() __builtin_amdgcn_s_setprio(0)

__global__ __launch_bounds__(512, 2) void gemm_q(
    const bf16_t* __restrict__ A, const bf16_t* __restrict__ Bm,
    float* __restrict__ C) {
  __shared__ __align__(16) char lds[131072];

  const int tid  = threadIdx.x;
  const int lane = tid & 63;
  const int wave = tid >> 6;
  const int wm   = wave >> 2;  // 0..1  (M half of block)
  const int wn   = wave & 3;   // 0..3  (N quarter of block)

  // T1: XCD-aware swizzle; 256 blocks % 8 == 0 -> bijective
  const int sbid = (blockIdx.x & 7) * 32 + (blockIdx.x >> 3);
  const int bm   = sbid >> 4;
  const int bn   = sbid & 15;

  const int frow = lane & 15;
  const int c16  = (lane >> 4) * 16;  // 16B chunk within 64B row

  // ds_read byte offsets within a ks-half [256][32] region (R4-verified
  // decorrelated swizzle: slot ^ ((row>>1)&3), 0 conflicts)
  int offA[4][2], offB[4];
#pragma unroll
  for (int q = 0; q < 4; ++q)
#pragma unroll
    for (int mi = 0; mi < 2; ++mi) {
      int r = wm * 128 + q * 32 + mi * 16 + frow;
      offA[q][mi] = r * 64 + (c16 ^ (((r >> 1) & 3) << 4));
    }
#pragma unroll
  for (int ni = 0; ni < 4; ++ni) {
    int r = wn * 64 + ni * 16 + frow;
    offB[ni] = r * 64 + (c16 ^ (((r >> 1) & 3) << 4));
  }

  // staging: write-side inverse of the read swizzle ((srow+128) keeps the
  // same ((row>>1)&3): bit7 is stripped by &3)
  const int srow   = tid >> 2;
  const int schunk = ((tid & 3) ^ ((srow >> 1) & 3)) * 8;
  const bf16_t* Ag = A  + (size_t)bm * 256 * 4096;
  const bf16_t* Bg = Bm + (size_t)bn * 256 * 4096;

  f32x4 acc[8][4] = {};
  bf16x8 a[2][2], b[4][2];

  // ---- prologue: A(0), B(0), B(1); VM(4) leaves B(1) in flight
  STAGE(Ag, 0,  A0_B);
  STAGE(Ag, 32, A0_B + HALF);
  STAGE(Bg, 0,  B0_B);
  STAGE(Bg, 32, B0_B + HALF);
  STAGE(Bg, 64, B1_B);
  STAGE(Bg, 96, B1_B + HALF);
  VM(4);
  BAR();

  int kb = 0;
#pragma unroll 1
  for (int i = 0; i < 31; ++i, kb += 128) {
    // ph1: tile t q0 (B hoist: read all B(t) + A q0) | stage A(t+1)ks0
    RDB(B0_B); RDA(A0_B, 0);
    STAGE(Ag, kb + 64, A1_B);
    BAR(); LGKM0(); PRIO1(); MFMAQ(0); PRIO0(); BAR();
    // ph2: tile t q1 | stage A(t+1)ks1
    RDA(A0_B, 1);
    STAGE(Ag, kb + 96, A1_B + HALF);
    BAR(); LGKM0(); PRIO1(); MFMAQ(1); PRIO0(); BAR();
    // ph3: tile t q2 | stage B(t+2)ks0   [B0 dead since ph1]
    RDA(A0_B, 2);
    STAGE(Bg, kb + 128, B0_B);
    BAR(); LGKM0(); PRIO1(); MFMAQ(2); PRIO0(); BAR();
    // ph4: tile t q3 | stage B(t+2)ks1 | drain B1(prev)+A1(cur) for ph5
    RDA(A0_B, 3);
    STAGE(Bg, kb + 160, B0_B + HALF);
    BAR(); LGKM0(); PRIO1(); MFMAQ(3); PRIO0(); VM(4); BAR();
    // ph5: tile t+1 q0 (read all B(t+1) + A q0) | stage A(t+2)ks0
    RDB(B1_B); RDA(A1_B, 0);
    STAGE(Ag, kb + 128, A0_B);
    BAR(); LGKM0(); PRIO1(); MFMAQ(0); PRIO0(); BAR();
    // ph6: tile t+1 q1 | stage A(t+2)ks1
    RDA(A1_B, 1);
    STAGE(Ag, kb + 160, A0_B + HALF);
    BAR(); LGKM0(); PRIO1(); MFMAQ(1); PRIO0(); BAR();
    // ph7: tile t+1 q2 | stage B(t+3)ks0   [B1 dead since ph5]
    RDA(A1_B, 2);
    STAGE(Bg, kb + 192, B1_B);
    BAR(); LGKM0(); PRIO1(); MFMAQ(2); PRIO0(); BAR();
    // ph8: tile t+1 q3 | stage B(t+3)ks1 | drain B0+A0(t+2) for next ph1
    RDA(A1_B, 3);
    STAGE(Bg, kb + 224, B1_B + HALF);
    BAR(); LGKM0(); PRIO1(); MFMAQ(3); PRIO0(); VM(4); BAR();
  }

  // ---- epilogue peel (t=62,63; kb == 3968): stages only A(63), VM(0)@ph4
  RDB(B0_B); RDA(A0_B, 0);
  STAGE(Ag, 4032, A1_B);                     // A(63)ks0
  BAR(); LGKM0(); PRIO1(); MFMAQ(0); PRIO0(); BAR();
  RDA(A0_B, 1);
  STAGE(Ag, 4064, A1_B + HALF);              // A(63)ks1
  BAR(); LGKM0(); PRIO1(); MFMAQ(1); PRIO0(); BAR();
  RDA(A0_B, 2);
  BAR(); LGKM0(); PRIO1(); MFMAQ(2); PRIO0(); BAR();
  RDA(A0_B, 3);
  BAR(); LGKM0(); PRIO1(); MFMAQ(3); PRIO0(); VM(0); BAR();
  RDB(B1_B); RDA(A1_B, 0);
  BAR(); LGKM0(); PRIO1(); MFMAQ(0); PRIO0(); BAR();
  RDA(A1_B, 1);
  BAR(); LGKM0(); PRIO1(); MFMAQ(1); PRIO0(); BAR();
  RDA(A1_B, 2);
  BAR(); LGKM0(); PRIO1(); MFMAQ(2); PRIO0(); BAR();
  RDA(A1_B, 3);
  LGKM0(); PRIO1(); MFMAQ(3); PRIO0();

  // ---- C write (D layout: col = lane&15, row = (lane>>4)*4 + jj);
  // acc[m] <-> M-row block wm*128 + m*16 (m = 2q+mi).
#pragma unroll
  for (int m = 0; m < 8; ++m)
#pragma unroll
    for (int ni = 0; ni < 4; ++ni) {
      const int row = bm * 256 + wm * 128 + m * 16 + (lane >> 4) * 4;
      const int col = bn * 256 + wn * 64 + ni * 16 + frow;
#pragma unroll
      for (int jj = 0; jj < 4; ++jj)
        C[(size_t)(row + jj) * 4096 + col] = acc[m][ni][jj];
    }
}

// ---------------------------------------------------------------------------
extern "C" void kernel_launch(void* const* d_in, const int* in_sizes, int n_in,
                              void* d_out, int out_size, void* d_ws, size_t ws_size,
                              hipStream_t stream) {
  const float* x     = (const float*)d_in[0];
  const float* wvals = (const float*)d_in[1];
  const int*   idx   = (const int*)d_in[2];   // (2, nnz): rows then cols
  const int*   mk    = (const int*)d_in[3];   // bool -> int32 on device (R1)
  const int    nnz   = in_sizes[1];

  // ws: [0,32MB) = W bf16, [32MB,64MB) = x bf16.
  bf16_t* Wbf = (bf16_t*)d_ws;
  bf16_t* xbf = (bf16_t*)((char*)d_ws + (size_t)OUT_F * IN_F * sizeof(bf16_t));

  const size_t needed = (size_t)OUT_F * IN_F * 2 + (size_t)BATCH * IN_F * 2;
  if (ws_size < needed) return;

  // 1. zero bf16 W via DMA memset (stream-ordered before scatter)
  hipMemsetAsync(Wbf, 0, (size_t)OUT_F * IN_F * sizeof(bf16_t), stream);

  // 2. fused: atomics issued FIRST (fire-and-forget), cvt streams under them
  scatter_cvtx<<<2048, 256, 0, stream>>>(
      wvals, idx, idx + nnz, mk, (unsigned*)Wbf, nnz,
      (const float4*)x, (uint4*)xbf);

  // 3. y = x @ W^T (frozen R13 quadrant/B-hoist schedule)
  gemm_q<<<256, 512, 0, stream>>>(xbf, Wbf, (float*)d_out);
}